// Round 8
// baseline (637.142 us; speedup 1.0000x reference)
//
#include <hip/hip_runtime.h>

// DGCNN on MI355X — round 8: k3 = R6 shape + cross-group software pipeline;
// k2 = R6 + LDS-transposed coalesced stores.
// R7 lesson: waves must keep a SMALL weight working set (2 n-tiles, 16KB) and
// read A-frags from LDS; R7's all-n-tiles-per-wave thrashed L1 and regressed.
// k3 now: block = 16 nodes, 4 iterations over one 32KB LDS tile; next group's
// random B3 gather is issued into registers right after the barrier, landing
// during the current group's MFMA phase. __launch_bounds__(256,4) pins VGPR<=128.
//   concat(a, b-a) @ W + bias = a @ (Wt-Wb) + b @ Wb + bias
//   conv2 gathers h1 with NODE ids -> only h1[0:N] rows needed

#define NN 100000
#define KNB 16
#define EE (NN * KNB)

// weight fragment bases (units of 512 ushorts = one 64-lane x 8-bf16 frag)
#define W2F 0     // W2  [64][64]   : 2 kc x 4 nt  = 8
#define W3F 8     // W3X [64][256]  : 2 kc x 16 nt = 32  (cols 0-127: W3t-W3b, 128-255: W3b)
#define W4F 40    // W4  [128][128] : 4 kc x 8 nt  = 32
#define W5F 72    // W5  [128][128] : 4 kc x 8 nt  = 32
#define W6F 104   // W6  [128][48p] : 4 kc x 3 nt  = 12
#define NFRAG 116

typedef float floatx4 __attribute__((ext_vector_type(4)));
typedef __bf16 bf16x8 __attribute__((ext_vector_type(8)));

static __device__ __forceinline__ unsigned f2bf_rne_u(float f) {
    unsigned u = __float_as_uint(f);
    return (u + 0x7FFFu + ((u >> 16) & 1u)) >> 16;
}
static __device__ __forceinline__ float bfu2f(unsigned h) {
    return __uint_as_float(h << 16);
}

// split a pair of fp32 into packed bf16 hi (truncate) + bf16 lo (RNE of exact
// residual). hp = {lo16: a_hi, hi16: b_hi}; one v_perm_b32 per pack.
static __device__ __forceinline__ void split_pack2(float a, float b,
                                                   unsigned& hp, unsigned& lp) {
    unsigned ua = __float_as_uint(a), ub = __float_as_uint(b);
    hp = __builtin_amdgcn_perm(ub, ua, 0x07060302u);        // [b.b3 b.b2 a.b3 a.b2]
    float ra = a - __uint_as_float(ua & 0xFFFF0000u);       // exact residual
    float rb = b - __uint_as_float(ub & 0xFFFF0000u);
    unsigned la = __float_as_uint(ra), lb = __float_as_uint(rb);
    la = la + 0x7FFFu + ((la >> 16) & 1u);                  // RNE round point
    lb = lb + 0x7FFFu + ((lb >> 16) & 1u);
    lp = __builtin_amdgcn_perm(lb, la, 0x07060302u);
}

// split 8 fp32 -> bf16x8 hi + bf16x8 lo
static __device__ __forceinline__ void split8(float4 f0, float4 f1,
                                              bf16x8& ah, bf16x8& al) {
    unsigned hd[4], ld[4];
    split_pack2(f0.x, f0.y, hd[0], ld[0]);
    split_pack2(f0.z, f0.w, hd[1], ld[1]);
    split_pack2(f1.x, f1.y, hd[2], ld[2]);
    split_pack2(f1.z, f1.w, hd[3], ld[3]);
    uint4 H = {hd[0], hd[1], hd[2], hd[3]};
    uint4 L = {ld[0], ld[1], ld[2], ld[3]};
    ah = __builtin_bit_cast(bf16x8, H);
    al = __builtin_bit_cast(bf16x8, L);
}

// ---------------- KW: pre-split all weights into frag-ordered bf16 hi/lo ------
// Frag (kc,nt): lane l holds W[kc*32 + (l>>4)*8 + j][nt*16 + (l&15)], j=0..7.
__global__ __launch_bounds__(256) void kw_kernel(
    const float* __restrict__ W2, const float* __restrict__ W3,
    const float* __restrict__ W4, const float* __restrict__ W5,
    const float* __restrict__ W6,
    unsigned short* __restrict__ WH, unsigned short* __restrict__ WL)
{
    int d = blockIdx.x * 256 + threadIdx.x;
    if (d >= NFRAG * 64) return;
    int f = d >> 6, l = d & 63, c = l & 15, q = l >> 4;
    float v[8];
    if (f < W3F) {                    // W2 [64][64]
        int fx = f - W2F, kc = fx >> 2, nt = fx & 3;
        int k0 = kc * 32 + q * 8, n = nt * 16 + c;
#pragma unroll
        for (int j = 0; j < 8; ++j) v[j] = W2[(k0 + j) * 64 + n];
    } else if (f < W4F) {             // W3X [64][256]
        int fx = f - W3F, kc = fx >> 4, nt = fx & 15;
        int k0 = kc * 32 + q * 8, n = nt * 16 + c;
#pragma unroll
        for (int j = 0; j < 8; ++j) {
            int k = k0 + j;
            v[j] = (n < 128) ? (W3[k * 128 + n] - W3[(64 + k) * 128 + n])
                             : W3[(64 + k) * 128 + (n - 128)];
        }
    } else if (f < W5F) {             // W4 [128][128]
        int fx = f - W4F, kc = fx >> 3, nt = fx & 7;
        int k0 = kc * 32 + q * 8, n = nt * 16 + c;
#pragma unroll
        for (int j = 0; j < 8; ++j) v[j] = W4[(k0 + j) * 128 + n];
    } else if (f < W6F) {             // W5 [128][128]
        int fx = f - W5F, kc = fx >> 3, nt = fx & 7;
        int k0 = kc * 32 + q * 8, n = nt * 16 + c;
#pragma unroll
        for (int j = 0; j < 8; ++j) v[j] = W5[(k0 + j) * 128 + n];
    } else {                          // W6 [128][40] padded to 48
        int fx = f - W6F, kc = fx / 3, nt = fx % 3;
        int k0 = kc * 32 + q * 8, n = nt * 16 + c;
#pragma unroll
        for (int j = 0; j < 8; ++j)
            v[j] = (n < 40) ? W6[(k0 + j) * 40 + n] : 0.0f;
    }
    unsigned hs[8], ls[8];
#pragma unroll
    for (int j = 0; j < 8; ++j) {
        unsigned h = f2bf_rne_u(v[j]);
        float r = v[j] - bfu2f(h);
        hs[j] = h;
        ls[j] = f2bf_rne_u(r);
    }
    uint4 H, L;
    H.x = hs[0] | (hs[1] << 16); H.y = hs[2] | (hs[3] << 16);
    H.z = hs[4] | (hs[5] << 16); H.w = hs[6] | (hs[7] << 16);
    L.x = ls[0] | (ls[1] << 16); L.y = ls[2] | (ls[3] << 16);
    L.z = ls[4] | (ls[5] << 16); L.w = ls[6] | (ls[7] << 16);
    *(uint4*)(WH + (size_t)d * 8) = H;
    *(uint4*)(WL + (size_t)d * 8) = L;
}

// ---------------- K1: A1 = x@(W1t-W1b)+b1, B1 = x@W1b ----------------
__global__ __launch_bounds__(256) void k1_kernel(
    const float* __restrict__ x, const float* __restrict__ W1,
    const float* __restrict__ b1, float* __restrict__ A1, float* __restrict__ B1)
{
    int gid = blockIdx.x * 256 + threadIdx.x;
    int n = gid >> 6;
    int j = gid & 63;
    const float* xr = x + n * 16;
    float acc_a = b1[j];
    float acc_b = 0.0f;
#pragma unroll
    for (int k = 0; k < 16; ++k) {
        float xv = xr[k];
        float wt = W1[k * 64 + j];
        float wb = W1[(16 + k) * 64 + j];
        acc_a = fmaf(xv, wt - wb, acc_a);
        acc_b = fmaf(xv, wb, acc_b);
    }
    A1[n * 64 + j] = acc_a;
    B1[n * 64 + j] = acc_b;
}

// ---------------- K2 (MFMA): 64 rows/block; t=relu(A1+B1[col]) -> h=relu(t@W2+b2)
//   -> A3 = h@(W3t-W3b)+b3, B3 = h@W3b. Stores coalesced via LDS transpose. ----
__global__ __launch_bounds__(256) void k2_kernel(
    const int* __restrict__ col,
    const float* __restrict__ A1, const float* __restrict__ B1,
    const unsigned short* __restrict__ WH, const unsigned short* __restrict__ WL,
    const float* __restrict__ b2, const float* __restrict__ b3,
    float* __restrict__ A3, float* __restrict__ B3)
{
    __shared__ __align__(16) float smem[8448];    // 33 KB: tF|hF, then 64x132 Tr
    float* tF = smem;                              // 4096 floats
    float* hF = smem + 4096;                       // 4096 floats
    float* Tr = smem;                              // 64 x 132 transpose buffer
    const int t = threadIdx.x;
    const int i0 = blockIdx.x * 64;

    // phase A: t[row] = relu(A1[i>>4] + B1[col[i]]) -> tF frag layout
    {
        const int row = t & 63, part = t >> 6;
        int i = i0 + row;                 // tail reads valid (i < EE), stores guarded
        int nn = i >> 4;
        int ci = col[i];
        const float* ar = A1 + (size_t)nn * 64 + part * 16;
        const float* br = B1 + (size_t)ci * 64 + part * 16;
        int mt = row >> 4, m = row & 15, kc = part >> 1;
        float* base = tF + (mt * 2 + kc) * 512 + m * 8;
#pragma unroll
        for (int h = 0; h < 2; ++h) {
            int qq = (part & 1) * 2 + h;
            float4 a0 = *(const float4*)(ar + h * 8);
            float4 b0 = *(const float4*)(br + h * 8);
            float4 a1 = *(const float4*)(ar + h * 8 + 4);
            float4 b1v = *(const float4*)(br + h * 8 + 4);
            float4 r0, r1;
            r0.x = fmaxf(a0.x + b0.x, 0.0f); r0.y = fmaxf(a0.y + b0.y, 0.0f);
            r0.z = fmaxf(a0.z + b0.z, 0.0f); r0.w = fmaxf(a0.w + b0.w, 0.0f);
            r1.x = fmaxf(a1.x + b1v.x, 0.0f); r1.y = fmaxf(a1.y + b1v.y, 0.0f);
            r1.z = fmaxf(a1.z + b1v.z, 0.0f); r1.w = fmaxf(a1.w + b1v.w, 0.0f);
            *(float4*)(base + qq * 128) = r0;
            *(float4*)(base + qq * 128 + 4) = r1;
        }
    }
    __syncthreads();

    const int w = __builtin_amdgcn_readfirstlane(t >> 6);   // wave = m-tile
    const int lane = t & 63;

    // GEMM1: h-tile rows w*16..+15; acc1[nt=0..3]
    floatx4 acc1[4];
#pragma unroll
    for (int nt = 0; nt < 4; ++nt) acc1[nt] = (floatx4){0.f, 0.f, 0.f, 0.f};
#pragma unroll
    for (int kc = 0; kc < 2; ++kc) {
        const float* ap = tF + (w * 2 + kc) * 512 + lane * 8;
        bf16x8 ah, al;
        split8(*(const float4*)ap, *(const float4*)(ap + 4), ah, al);
#pragma unroll
        for (int nt = 0; nt < 4; ++nt) {
            size_t fb = (size_t)(W2F + kc * 4 + nt) * 512 + lane * 8;
            bf16x8 bh = __builtin_bit_cast(bf16x8, *(const uint4*)(WH + fb));
            bf16x8 bl = __builtin_bit_cast(bf16x8, *(const uint4*)(WL + fb));
            acc1[nt] = __builtin_amdgcn_mfma_f32_16x16x32_bf16(ah, bh, acc1[nt], 0, 0, 0);
            acc1[nt] = __builtin_amdgcn_mfma_f32_16x16x32_bf16(ah, bl, acc1[nt], 0, 0, 0);
            acc1[nt] = __builtin_amdgcn_mfma_f32_16x16x32_bf16(al, bh, acc1[nt], 0, 0, 0);
        }
    }
    // h = relu(acc1 + b2) -> hF frag layout (wave-local rows -> no barrier)
    {
        const int qq = lane >> 4, cc = lane & 15;
#pragma unroll
        for (int nt = 0; nt < 4; ++nt) {
            float bv = b2[nt * 16 + cc];
            int colIdx = nt * 16 + cc;
            int kc2 = colIdx >> 5, q2 = (colIdx >> 3) & 3, jj = cc & 7;
            float* dst = hF + (w * 2 + kc2) * 512 + q2 * 128 + jj;
#pragma unroll
            for (int r = 0; r < 4; ++r)
                dst[(qq * 4 + r) * 8] = fmaxf(acc1[nt][r] + bv, 0.0f);
        }
    }
    // GEMM2: [16 x 64] @ W3X[64 x 256]; acc2[nt=0..15]
    floatx4 acc2[16];
#pragma unroll
    for (int nt = 0; nt < 16; ++nt) acc2[nt] = (floatx4){0.f, 0.f, 0.f, 0.f};
#pragma unroll
    for (int kc = 0; kc < 2; ++kc) {
        const float* ap = hF + (w * 2 + kc) * 512 + lane * 8;
        bf16x8 ah, al;
        split8(*(const float4*)ap, *(const float4*)(ap + 4), ah, al);
#pragma unroll
        for (int nt = 0; nt < 16; ++nt) {
            size_t fb = (size_t)(W3F + kc * 16 + nt) * 512 + lane * 8;
            bf16x8 bh = __builtin_bit_cast(bf16x8, *(const uint4*)(WH + fb));
            bf16x8 bl = __builtin_bit_cast(bf16x8, *(const uint4*)(WL + fb));
            acc2[nt] = __builtin_amdgcn_mfma_f32_16x16x32_bf16(ah, bh, acc2[nt], 0, 0, 0);
            acc2[nt] = __builtin_amdgcn_mfma_f32_16x16x32_bf16(ah, bl, acc2[nt], 0, 0, 0);
            acc2[nt] = __builtin_amdgcn_mfma_f32_16x16x32_bf16(al, bh, acc2[nt], 0, 0, 0);
        }
    }
    // store via LDS transpose: pass 0 = A3 (+b3), pass 1 = B3. Coalesced rows.
    __syncthreads();                      // all tF/hF reads complete
    {
        const int qq = lane >> 4, cc = lane & 15;
#pragma unroll
        for (int h = 0; h < 2; ++h) {
#pragma unroll
            for (int ntl = 0; ntl < 8; ++ntl) {
                int nt = h * 8 + ntl;
                int n = ntl * 16 + cc;
                float bv = (h == 0) ? b3[n] : 0.0f;
#pragma unroll
                for (int r = 0; r < 4; ++r)
                    Tr[(w * 16 + qq * 4 + r) * 132 + n] = acc2[nt][r] + bv;
            }
            __syncthreads();
            {
                int rowL = t & 63, cg = t >> 6;
                int i = i0 + rowL;
                if (i < NN) {
                    float* dst = (h == 0 ? A3 : B3) + (size_t)i * 128 + cg * 32;
                    const float* src = Tr + rowL * 132 + cg * 32;
#pragma unroll
                    for (int j = 0; j < 32; j += 4)
                        *(float4*)(dst + j) = *(const float4*)(src + j);
                }
            }
            if (h == 0) __syncthreads();
        }
    }
}

// ---------------- K3: R6 body, pipelined over 4 groups of 4 nodes -------------
// Block = 16 nodes. One 32KB LDS tile reused; next group's random B3 gather is
// issued into 32 VGPRs right after the barrier, landing during current MFMA.
__global__ __launch_bounds__(256, 4) void k3_kernel(
    const int* __restrict__ col,
    const float* __restrict__ A3, const float* __restrict__ B3,
    const unsigned short* __restrict__ WH, const unsigned short* __restrict__ WL,
    const float* __restrict__ b4, float* __restrict__ g)
{
    __shared__ __align__(16) unsigned short aHi[8192];   // 16 KB
    __shared__ __align__(16) unsigned short aLo[8192];   // 16 KB
    const int t = threadIdx.x;
    const int row = t & 63;
    const int kcm = t >> 6;
    const int lane = t & 63;
    const int wv = t >> 6;
    const int ntb = wv * 2;
    const int node00 = blockIdx.x * 16;

    // prefetch group 0's B3 slab
    float4 bpre[8];
    {
        const int c = col[node00 * KNB + row];
        const float* br = B3 + (size_t)c * 128 + kcm * 32;
#pragma unroll
        for (int q = 0; q < 4; ++q) {
            bpre[2 * q]     = *(const float4*)(br + q * 8);
            bpre[2 * q + 1] = *(const float4*)(br + q * 8 + 4);
        }
    }

    for (int it = 0; it < 4; ++it) {
        const int node0 = node00 + it * 4;
        // split + LDS write (A3 direct: 16 lanes share each 32B slab -> L1)
        {
            const int mt = row >> 4, m = row & 15;
            const float* ar = A3 + (size_t)(node0 + mt) * 128 + kcm * 32;
            const int base = (mt * 4 + kcm) * 512 + m * 8;
#pragma unroll
            for (int q = 0; q < 4; ++q) {
                float4 a0 = *(const float4*)(ar + q * 8);
                float4 a1 = *(const float4*)(ar + q * 8 + 4);
                float4 b0 = bpre[2 * q], b1 = bpre[2 * q + 1];
                float v0 = fmaxf(a0.x + b0.x, 0.0f), v1 = fmaxf(a0.y + b0.y, 0.0f);
                float v2 = fmaxf(a0.z + b0.z, 0.0f), v3 = fmaxf(a0.w + b0.w, 0.0f);
                float v4 = fmaxf(a1.x + b1.x, 0.0f), v5 = fmaxf(a1.y + b1.y, 0.0f);
                float v6 = fmaxf(a1.z + b1.z, 0.0f), v7 = fmaxf(a1.w + b1.w, 0.0f);
                uint4 H, L;
                split_pack2(v0, v1, H.x, L.x);
                split_pack2(v2, v3, H.y, L.y);
                split_pack2(v4, v5, H.z, L.z);
                split_pack2(v6, v7, H.w, L.w);
                *(uint4*)(aHi + base + q * 128) = H;
                *(uint4*)(aLo + base + q * 128) = L;
            }
        }
        __syncthreads();

        // issue next group's gather NOW; lands during the MFMA phase below
        if (it < 3) {
            const int c = col[(node0 + 4) * KNB + row];
            const float* br = B3 + (size_t)c * 128 + kcm * 32;
#pragma unroll
            for (int q = 0; q < 4; ++q) {
                bpre[2 * q]     = *(const float4*)(br + q * 8);
                bpre[2 * q + 1] = *(const float4*)(br + q * 8 + 4);
            }
        }

        // MFMA phase: wave wv owns n-tiles {2wv, 2wv+1} x all 4 m-tiles
        floatx4 acc[4][2];
#pragma unroll
        for (int mt = 0; mt < 4; ++mt)
#pragma unroll
            for (int ntl = 0; ntl < 2; ++ntl)
                acc[mt][ntl] = (floatx4){0.0f, 0.0f, 0.0f, 0.0f};

#pragma unroll
        for (int kc = 0; kc < 4; ++kc) {
            bf16x8 bh[2], bl[2];
#pragma unroll
            for (int ntl = 0; ntl < 2; ++ntl) {
                int nt = ntb + ntl;
                bh[ntl] = __builtin_bit_cast(bf16x8,
                    *(const uint4*)(WH + (size_t)((kc * 8 + nt) * 64 + lane) * 8));
                bl[ntl] = __builtin_bit_cast(bf16x8,
                    *(const uint4*)(WL + (size_t)((kc * 8 + nt) * 64 + lane) * 8));
            }
            bf16x8 ah[4], al[4];
#pragma unroll
            for (int mt = 0; mt < 4; ++mt) {
                ah[mt] = __builtin_bit_cast(bf16x8,
                    *(const uint4*)(aHi + (mt * 4 + kc) * 512 + lane * 8));
                al[mt] = __builtin_bit_cast(bf16x8,
                    *(const uint4*)(aLo + (mt * 4 + kc) * 512 + lane * 8));
            }
#pragma unroll
            for (int mt = 0; mt < 4; ++mt)
#pragma unroll
                for (int ntl = 0; ntl < 2; ++ntl) {
                    acc[mt][ntl] = __builtin_amdgcn_mfma_f32_16x16x32_bf16(
                        ah[mt], bh[ntl], acc[mt][ntl], 0, 0, 0);
                    acc[mt][ntl] = __builtin_amdgcn_mfma_f32_16x16x32_bf16(
                        ah[mt], bl[ntl], acc[mt][ntl], 0, 0, 0);
                    acc[mt][ntl] = __builtin_amdgcn_mfma_f32_16x16x32_bf16(
                        al[mt], bh[ntl], acc[mt][ntl], 0, 0, 0);
                }
        }

        // K-max in-register + g store. D layout: row=(lane>>4)*4+reg, col=lane&15.
#pragma unroll
        for (int mt = 0; mt < 4; ++mt)
#pragma unroll
            for (int ntl = 0; ntl < 2; ++ntl) {
                floatx4 a = acc[mt][ntl];
                float mm = fmaxf(fmaxf(a[0], a[1]), fmaxf(a[2], a[3]));
                mm = fmaxf(mm, __shfl_xor(mm, 16));
                mm = fmaxf(mm, __shfl_xor(mm, 32));
                if (lane < 16) {
                    int ccol = (ntb + ntl) * 16 + lane;
                    g[(size_t)(node0 + mt) * 128 + ccol] =
                        fmaxf(mm + b4[ccol], 0.0f);
                }
            }
        __syncthreads();   // all MFMA reads of aHi/aLo done before next overwrite
    }
}

// ---------------- K4 (MFMA): 64 nodes/block; out = relu(g@W5+b5)@W6+b6 --------
__global__ __launch_bounds__(256) void k4_kernel(
    const float* __restrict__ g,
    const unsigned short* __restrict__ WH, const unsigned short* __restrict__ WL,
    const float* __restrict__ b5, const float* __restrict__ b6,
    float* __restrict__ out)
{
    __shared__ __align__(16) float gF[16 * 512];   // 32 KB, frag-contig fp32
    const int t = threadIdx.x;
    const int n0 = blockIdx.x * 64;

    // phase A: stage g rows into frag layout (clamp tail)
    {
        const int row = t & 63, part = t >> 6;    // part == kc
        int gn = n0 + row; if (gn >= NN) gn = NN - 1;
        const float* gr = g + (size_t)gn * 128 + part * 32;
        int mt = row >> 4, m = row & 15;
        float* base = gF + (mt * 4 + part) * 512 + m * 8;
#pragma unroll
        for (int qq = 0; qq < 4; ++qq) {
            *(float4*)(base + qq * 128)     = *(const float4*)(gr + qq * 8);
            *(float4*)(base + qq * 128 + 4) = *(const float4*)(gr + qq * 8 + 4);
        }
    }
    __syncthreads();

    const int w = __builtin_amdgcn_readfirstlane(t >> 6);
    const int lane = t & 63;

    // GEMM1: t1-tile rows w*16..+15; acc1[nt=0..7]
    floatx4 acc1[8];
#pragma unroll
    for (int nt = 0; nt < 8; ++nt) acc1[nt] = (floatx4){0.f, 0.f, 0.f, 0.f};
#pragma unroll
    for (int kc = 0; kc < 4; ++kc) {
        const float* ap = gF + (w * 4 + kc) * 512 + lane * 8;
        bf16x8 ah, al;
        split8(*(const float4*)ap, *(const float4*)(ap + 4), ah, al);
#pragma unroll
        for (int nt = 0; nt < 8; ++nt) {
            size_t fb = (size_t)(W5F + kc * 8 + nt) * 512 + lane * 8;
            bf16x8 bh = __builtin_bit_cast(bf16x8, *(const uint4*)(WH + fb));
            bf16x8 bl = __builtin_bit_cast(bf16x8, *(const uint4*)(WL + fb));
            acc1[nt] = __builtin_amdgcn_mfma_f32_16x16x32_bf16(ah, bh, acc1[nt], 0, 0, 0);
            acc1[nt] = __builtin_amdgcn_mfma_f32_16x16x32_bf16(ah, bl, acc1[nt], 0, 0, 0);
            acc1[nt] = __builtin_amdgcn_mfma_f32_16x16x32_bf16(al, bh, acc1[nt], 0, 0, 0);
        }
    }
    // t1 = relu(acc1 + b5) -> overwrite own frags (wave-local, reads done)
    {
        const int qq = lane >> 4, cc = lane & 15;
#pragma unroll
        for (int nt = 0; nt < 8; ++nt) {
            float bv = b5[nt * 16 + cc];
            int colIdx = nt * 16 + cc;
            int kc2 = colIdx >> 5, q2 = (colIdx >> 3) & 3, jj = cc & 7;
            float* dst = gF + (w * 4 + kc2) * 512 + q2 * 128 + jj;
#pragma unroll
            for (int r = 0; r < 4; ++r)
                dst[(qq * 4 + r) * 8] = fmaxf(acc1[nt][r] + bv, 0.0f);
        }
    }
    // GEMM2: [16 x 128] @ W6pad[128 x 48]; acc2[nt=0..2]
    floatx4 acc2[3];
#pragma unroll
    for (int nt = 0; nt < 3; ++nt) acc2[nt] = (floatx4){0.f, 0.f, 0.f, 0.f};
#pragma unroll
    for (int kc = 0; kc < 4; ++kc) {
        const float* ap = gF + (w * 4 + kc) * 512 + lane * 8;
        bf16x8 ah, al;
        split8(*(const float4*)ap, *(const float4*)(ap + 4), ah, al);
#pragma unroll
        for (int nt = 0; nt < 3; ++nt) {
            size_t fb = (size_t)(W6F + kc * 3 + nt) * 512 + lane * 8;
            bf16x8 bh = __builtin_bit_cast(bf16x8, *(const uint4*)(WH + fb));
            bf16x8 bl = __builtin_bit_cast(bf16x8, *(const uint4*)(WL + fb));
            acc2[nt] = __builtin_amdgcn_mfma_f32_16x16x32_bf16(ah, bh, acc2[nt], 0, 0, 0);
            acc2[nt] = __builtin_amdgcn_mfma_f32_16x16x32_bf16(ah, bl, acc2[nt], 0, 0, 0);
            acc2[nt] = __builtin_amdgcn_mfma_f32_16x16x32_bf16(al, bh, acc2[nt], 0, 0, 0);
        }
    }
    // store out (cols >= 40 are pad)
    {
        const int qq = lane >> 4, cc = lane & 15;
#pragma unroll
        for (int nt = 0; nt < 3; ++nt) {
            int n = nt * 16 + cc;
            if (n < 40) {
                float bv = b6[n];
#pragma unroll
                for (int r = 0; r < 4; ++r) {
                    int i = n0 + w * 16 + qq * 4 + r;
                    if (i < NN)
                        out[(size_t)i * 40 + n] = acc2[nt][r] + bv;
                }
            }
        }
    }
}

extern "C" void kernel_launch(void* const* d_in, const int* in_sizes, int n_in,
                              void* d_out, int out_size, void* d_ws, size_t ws_size,
                              hipStream_t stream)
{
    const float* x  = (const float*)d_in[0];
    const int* ei   = (const int*)d_in[1];
    const int* col  = ei + EE;
    const float* W1 = (const float*)d_in[2];
    const float* b1 = (const float*)d_in[3];
    const float* W2 = (const float*)d_in[4];
    const float* b2 = (const float*)d_in[5];
    const float* W3 = (const float*)d_in[6];
    const float* b3 = (const float*)d_in[7];
    const float* W4 = (const float*)d_in[8];
    const float* b4 = (const float*)d_in[9];
    const float* W5 = (const float*)d_in[10];
    const float* b5 = (const float*)d_in[11];
    const float* W6 = (const float*)d_in[12];
    const float* b6 = (const float*)d_in[13];
    float* out = (float*)d_out;

    float* A1 = (float*)d_ws;                    // [N,64]
    float* B1 = A1 + (size_t)NN * 64;            // [N,64]
    float* A3 = B1 + (size_t)NN * 64;            // [N,128]
    float* B3 = A3 + (size_t)NN * 128;           // [N,128]
    unsigned short* WH = (unsigned short*)(B3 + (size_t)NN * 128);  // [116*512]
    unsigned short* WL = WH + NFRAG * 512;
    float* g  = A1;                              // [N,128] reuses A1/B1 (dead after k2)

    kw_kernel<<<(NFRAG * 64 + 255) / 256, 256, 0, stream>>>(W2, W3, W4, W5, W6, WH, WL);
    k1_kernel<<<NN * 64 / 256, 256, 0, stream>>>(x, W1, b1, A1, B1);
    k2_kernel<<<(NN + 63) / 64, 256, 0, stream>>>(col, A1, B1, WH, WL, b2, b3, A3, B3);
    k3_kernel<<<NN / 16, 256, 0, stream>>>(col, A3, B3,
                                           WH + (size_t)W4F * 512, WL + (size_t)W4F * 512,
                                           b4, g);
    k4_kernel<<<(NN + 63) / 64, 256, 0, stream>>>(g, WH, WL, b5, b6, out);
}

// Round 9
// 467.666 us; speedup vs baseline: 1.3624x; 1.3624x over previous
//
#include <hip/hip_runtime.h>

// DGCNN on MI355X — round 9: R8's pipelined k3 with the spill fixed.
// R8 post-mortem: WRITE_SIZE 50->326MB = scratch spill — bpre(32) + acc(32) +
// frags(48) ~ 145 VGPRs vs the 128 cap from __launch_bounds__(256,4).
// Fix: __launch_bounds__(256,3) -> ~170 VGPR cap, 3 blocks/CU; the register
// prefetch of the next group's random B3 gather now stays in registers and
// lands under the current group's MFMA phase. k2 reverted to R6 (transpose
// store was -16us). Weights frag-ordered bf16 hi/lo (kw), 3-product split GEMM.
//   concat(a, b-a) @ W + bias = a @ (Wt-Wb) + b @ Wb + bias
//   conv2 gathers h1 with NODE ids -> only h1[0:N] rows needed

#define NN 100000
#define KNB 16
#define EE (NN * KNB)

// weight fragment bases (units of 512 ushorts = one 64-lane x 8-bf16 frag)
#define W2F 0     // W2  [64][64]   : 2 kc x 4 nt  = 8
#define W3F 8     // W3X [64][256]  : 2 kc x 16 nt = 32  (cols 0-127: W3t-W3b, 128-255: W3b)
#define W4F 40    // W4  [128][128] : 4 kc x 8 nt  = 32
#define W5F 72    // W5  [128][128] : 4 kc x 8 nt  = 32
#define W6F 104   // W6  [128][48p] : 4 kc x 3 nt  = 12
#define NFRAG 116

typedef float floatx4 __attribute__((ext_vector_type(4)));
typedef __bf16 bf16x8 __attribute__((ext_vector_type(8)));

static __device__ __forceinline__ unsigned f2bf_rne_u(float f) {
    unsigned u = __float_as_uint(f);
    return (u + 0x7FFFu + ((u >> 16) & 1u)) >> 16;
}
static __device__ __forceinline__ float bfu2f(unsigned h) {
    return __uint_as_float(h << 16);
}

// split a pair of fp32 into packed bf16 hi (truncate) + bf16 lo (RNE of exact
// residual). hp = {lo16: a_hi, hi16: b_hi}; one v_perm_b32 per pack.
static __device__ __forceinline__ void split_pack2(float a, float b,
                                                   unsigned& hp, unsigned& lp) {
    unsigned ua = __float_as_uint(a), ub = __float_as_uint(b);
    hp = __builtin_amdgcn_perm(ub, ua, 0x07060302u);        // [b.b3 b.b2 a.b3 a.b2]
    float ra = a - __uint_as_float(ua & 0xFFFF0000u);       // exact residual
    float rb = b - __uint_as_float(ub & 0xFFFF0000u);
    unsigned la = __float_as_uint(ra), lb = __float_as_uint(rb);
    la = la + 0x7FFFu + ((la >> 16) & 1u);                  // RNE round point
    lb = lb + 0x7FFFu + ((lb >> 16) & 1u);
    lp = __builtin_amdgcn_perm(lb, la, 0x07060302u);
}

// split 8 fp32 -> bf16x8 hi + bf16x8 lo
static __device__ __forceinline__ void split8(float4 f0, float4 f1,
                                              bf16x8& ah, bf16x8& al) {
    unsigned hd[4], ld[4];
    split_pack2(f0.x, f0.y, hd[0], ld[0]);
    split_pack2(f0.z, f0.w, hd[1], ld[1]);
    split_pack2(f1.x, f1.y, hd[2], ld[2]);
    split_pack2(f1.z, f1.w, hd[3], ld[3]);
    uint4 H = {hd[0], hd[1], hd[2], hd[3]};
    uint4 L = {ld[0], ld[1], ld[2], ld[3]};
    ah = __builtin_bit_cast(bf16x8, H);
    al = __builtin_bit_cast(bf16x8, L);
}

// ---------------- KW: pre-split all weights into frag-ordered bf16 hi/lo ------
// Frag (kc,nt): lane l holds W[kc*32 + (l>>4)*8 + j][nt*16 + (l&15)], j=0..7.
__global__ __launch_bounds__(256) void kw_kernel(
    const float* __restrict__ W2, const float* __restrict__ W3,
    const float* __restrict__ W4, const float* __restrict__ W5,
    const float* __restrict__ W6,
    unsigned short* __restrict__ WH, unsigned short* __restrict__ WL)
{
    int d = blockIdx.x * 256 + threadIdx.x;
    if (d >= NFRAG * 64) return;
    int f = d >> 6, l = d & 63, c = l & 15, q = l >> 4;
    float v[8];
    if (f < W3F) {                    // W2 [64][64]
        int fx = f - W2F, kc = fx >> 2, nt = fx & 3;
        int k0 = kc * 32 + q * 8, n = nt * 16 + c;
#pragma unroll
        for (int j = 0; j < 8; ++j) v[j] = W2[(k0 + j) * 64 + n];
    } else if (f < W4F) {             // W3X [64][256]
        int fx = f - W3F, kc = fx >> 4, nt = fx & 15;
        int k0 = kc * 32 + q * 8, n = nt * 16 + c;
#pragma unroll
        for (int j = 0; j < 8; ++j) {
            int k = k0 + j;
            v[j] = (n < 128) ? (W3[k * 128 + n] - W3[(64 + k) * 128 + n])
                             : W3[(64 + k) * 128 + (n - 128)];
        }
    } else if (f < W5F) {             // W4 [128][128]
        int fx = f - W4F, kc = fx >> 3, nt = fx & 7;
        int k0 = kc * 32 + q * 8, n = nt * 16 + c;
#pragma unroll
        for (int j = 0; j < 8; ++j) v[j] = W4[(k0 + j) * 128 + n];
    } else if (f < W6F) {             // W5 [128][128]
        int fx = f - W5F, kc = fx >> 3, nt = fx & 7;
        int k0 = kc * 32 + q * 8, n = nt * 16 + c;
#pragma unroll
        for (int j = 0; j < 8; ++j) v[j] = W5[(k0 + j) * 128 + n];
    } else {                          // W6 [128][40] padded to 48
        int fx = f - W6F, kc = fx / 3, nt = fx % 3;
        int k0 = kc * 32 + q * 8, n = nt * 16 + c;
#pragma unroll
        for (int j = 0; j < 8; ++j)
            v[j] = (n < 40) ? W6[(k0 + j) * 40 + n] : 0.0f;
    }
    unsigned hs[8], ls[8];
#pragma unroll
    for (int j = 0; j < 8; ++j) {
        unsigned h = f2bf_rne_u(v[j]);
        float r = v[j] - bfu2f(h);
        hs[j] = h;
        ls[j] = f2bf_rne_u(r);
    }
    uint4 H, L;
    H.x = hs[0] | (hs[1] << 16); H.y = hs[2] | (hs[3] << 16);
    H.z = hs[4] | (hs[5] << 16); H.w = hs[6] | (hs[7] << 16);
    L.x = ls[0] | (ls[1] << 16); L.y = ls[2] | (ls[3] << 16);
    L.z = ls[4] | (ls[5] << 16); L.w = ls[6] | (ls[7] << 16);
    *(uint4*)(WH + (size_t)d * 8) = H;
    *(uint4*)(WL + (size_t)d * 8) = L;
}

// ---------------- K1: A1 = x@(W1t-W1b)+b1, B1 = x@W1b ----------------
__global__ __launch_bounds__(256) void k1_kernel(
    const float* __restrict__ x, const float* __restrict__ W1,
    const float* __restrict__ b1, float* __restrict__ A1, float* __restrict__ B1)
{
    int gid = blockIdx.x * 256 + threadIdx.x;
    int n = gid >> 6;
    int j = gid & 63;
    const float* xr = x + n * 16;
    float acc_a = b1[j];
    float acc_b = 0.0f;
#pragma unroll
    for (int k = 0; k < 16; ++k) {
        float xv = xr[k];
        float wt = W1[k * 64 + j];
        float wb = W1[(16 + k) * 64 + j];
        acc_a = fmaf(xv, wt - wb, acc_a);
        acc_b = fmaf(xv, wb, acc_b);
    }
    A1[n * 64 + j] = acc_a;
    B1[n * 64 + j] = acc_b;
}

// ---------------- K2 (MFMA, R6 version): 64 rows/block --------------------
__global__ __launch_bounds__(256) void k2_kernel(
    const int* __restrict__ col,
    const float* __restrict__ A1, const float* __restrict__ B1,
    const unsigned short* __restrict__ WH, const unsigned short* __restrict__ WL,
    const float* __restrict__ b2, const float* __restrict__ b3,
    float* __restrict__ A3, float* __restrict__ B3)
{
    __shared__ __align__(16) float tF[8 * 512];   // 16 KB, frag-contig fp32
    __shared__ __align__(16) float hF[8 * 512];   // 16 KB
    const int t = threadIdx.x;
    const int i0 = blockIdx.x * 64;

    // phase A: t[row] = relu(A1[i>>4] + B1[col[i]]) -> tF frag layout
    {
        const int row = t & 63, part = t >> 6;
        int i = i0 + row;                 // tail reads valid (i < EE), stores guarded
        int nn = i >> 4;
        int ci = col[i];
        const float* ar = A1 + (size_t)nn * 64 + part * 16;
        const float* br = B1 + (size_t)ci * 64 + part * 16;
        int mt = row >> 4, m = row & 15, kc = part >> 1;
        float* base = tF + (mt * 2 + kc) * 512 + m * 8;
#pragma unroll
        for (int h = 0; h < 2; ++h) {
            int qq = (part & 1) * 2 + h;
            float4 a0 = *(const float4*)(ar + h * 8);
            float4 b0 = *(const float4*)(br + h * 8);
            float4 a1 = *(const float4*)(ar + h * 8 + 4);
            float4 b1v = *(const float4*)(br + h * 8 + 4);
            float4 r0, r1;
            r0.x = fmaxf(a0.x + b0.x, 0.0f); r0.y = fmaxf(a0.y + b0.y, 0.0f);
            r0.z = fmaxf(a0.z + b0.z, 0.0f); r0.w = fmaxf(a0.w + b0.w, 0.0f);
            r1.x = fmaxf(a1.x + b1v.x, 0.0f); r1.y = fmaxf(a1.y + b1v.y, 0.0f);
            r1.z = fmaxf(a1.z + b1v.z, 0.0f); r1.w = fmaxf(a1.w + b1v.w, 0.0f);
            *(float4*)(base + qq * 128) = r0;
            *(float4*)(base + qq * 128 + 4) = r1;
        }
    }
    __syncthreads();

    const int w = __builtin_amdgcn_readfirstlane(t >> 6);   // wave = m-tile
    const int lane = t & 63;

    // GEMM1: h-tile rows w*16..+15; acc1[nt=0..3]
    floatx4 acc1[4];
#pragma unroll
    for (int nt = 0; nt < 4; ++nt) acc1[nt] = (floatx4){0.f, 0.f, 0.f, 0.f};
#pragma unroll
    for (int kc = 0; kc < 2; ++kc) {
        const float* ap = tF + (w * 2 + kc) * 512 + lane * 8;
        bf16x8 ah, al;
        split8(*(const float4*)ap, *(const float4*)(ap + 4), ah, al);
#pragma unroll
        for (int nt = 0; nt < 4; ++nt) {
            size_t fb = (size_t)(W2F + kc * 4 + nt) * 512 + lane * 8;
            bf16x8 bh = __builtin_bit_cast(bf16x8, *(const uint4*)(WH + fb));
            bf16x8 bl = __builtin_bit_cast(bf16x8, *(const uint4*)(WL + fb));
            acc1[nt] = __builtin_amdgcn_mfma_f32_16x16x32_bf16(ah, bh, acc1[nt], 0, 0, 0);
            acc1[nt] = __builtin_amdgcn_mfma_f32_16x16x32_bf16(ah, bl, acc1[nt], 0, 0, 0);
            acc1[nt] = __builtin_amdgcn_mfma_f32_16x16x32_bf16(al, bh, acc1[nt], 0, 0, 0);
        }
    }
    // h = relu(acc1 + b2) -> hF frag layout (wave-local rows -> no barrier)
    {
        const int qq = lane >> 4, cc = lane & 15;
#pragma unroll
        for (int nt = 0; nt < 4; ++nt) {
            float bv = b2[nt * 16 + cc];
            int colIdx = nt * 16 + cc;
            int kc2 = colIdx >> 5, q2 = (colIdx >> 3) & 3, jj = cc & 7;
            float* dst = hF + (w * 2 + kc2) * 512 + q2 * 128 + jj;
#pragma unroll
            for (int r = 0; r < 4; ++r)
                dst[(qq * 4 + r) * 8] = fmaxf(acc1[nt][r] + bv, 0.0f);
        }
    }
    // GEMM2: [16 x 64] @ W3X[64 x 256]; acc2[nt=0..15]
    floatx4 acc2[16];
#pragma unroll
    for (int nt = 0; nt < 16; ++nt) acc2[nt] = (floatx4){0.f, 0.f, 0.f, 0.f};
#pragma unroll
    for (int kc = 0; kc < 2; ++kc) {
        const float* ap = hF + (w * 2 + kc) * 512 + lane * 8;
        bf16x8 ah, al;
        split8(*(const float4*)ap, *(const float4*)(ap + 4), ah, al);
#pragma unroll
        for (int nt = 0; nt < 16; ++nt) {
            size_t fb = (size_t)(W3F + kc * 16 + nt) * 512 + lane * 8;
            bf16x8 bh = __builtin_bit_cast(bf16x8, *(const uint4*)(WH + fb));
            bf16x8 bl = __builtin_bit_cast(bf16x8, *(const uint4*)(WL + fb));
            acc2[nt] = __builtin_amdgcn_mfma_f32_16x16x32_bf16(ah, bh, acc2[nt], 0, 0, 0);
            acc2[nt] = __builtin_amdgcn_mfma_f32_16x16x32_bf16(ah, bl, acc2[nt], 0, 0, 0);
            acc2[nt] = __builtin_amdgcn_mfma_f32_16x16x32_bf16(al, bh, acc2[nt], 0, 0, 0);
        }
    }
    // store: cols 0-127 -> A3 (+b3), 128-255 -> B3
    {
        const int qq = lane >> 4, cc = lane & 15;
#pragma unroll
        for (int nt = 0; nt < 16; ++nt) {
            int n = nt * 16 + cc;
            float bv = (n < 128) ? b3[n] : 0.0f;
#pragma unroll
            for (int r = 0; r < 4; ++r) {
                int i = i0 + w * 16 + qq * 4 + r;
                if (i < NN) {
                    float vv = acc2[nt][r];
                    if (n < 128) A3[(size_t)i * 128 + n] = vv + bv;
                    else         B3[(size_t)i * 128 + (n - 128)] = vv;
                }
            }
        }
    }
}

// ---------------- K3: pipelined over 4 groups of 4 nodes, launch_bounds(256,3)
// Block = 16 nodes, one 32KB LDS tile reused; next group's random B3 gather
// prefetched into registers right after the barrier (fits in the ~170 cap).
__global__ __launch_bounds__(256, 3) void k3_kernel(
    const int* __restrict__ col,
    const float* __restrict__ A3, const float* __restrict__ B3,
    const unsigned short* __restrict__ WH, const unsigned short* __restrict__ WL,
    const float* __restrict__ b4, float* __restrict__ g)
{
    __shared__ __align__(16) unsigned short aHi[8192];   // 16 KB
    __shared__ __align__(16) unsigned short aLo[8192];   // 16 KB
    const int t = threadIdx.x;
    const int row = t & 63;
    const int kcm = t >> 6;
    const int lane = t & 63;
    const int wv = t >> 6;
    const int ntb = wv * 2;
    const int node00 = blockIdx.x * 16;

    // prefetch group 0's B3 slab
    float4 bpre[8];
    {
        const int c = col[node00 * KNB + row];
        const float* br = B3 + (size_t)c * 128 + kcm * 32;
#pragma unroll
        for (int q = 0; q < 4; ++q) {
            bpre[2 * q]     = *(const float4*)(br + q * 8);
            bpre[2 * q + 1] = *(const float4*)(br + q * 8 + 4);
        }
    }

    for (int it = 0; it < 4; ++it) {
        const int node0 = node00 + it * 4;
        // split + LDS write (A3 direct: 16 lanes share each 32B slab -> L1)
        {
            const int mt = row >> 4, m = row & 15;
            const float* ar = A3 + (size_t)(node0 + mt) * 128 + kcm * 32;
            const int base = (mt * 4 + kcm) * 512 + m * 8;
#pragma unroll
            for (int q = 0; q < 4; ++q) {
                float4 a0 = *(const float4*)(ar + q * 8);
                float4 a1 = *(const float4*)(ar + q * 8 + 4);
                float4 b0 = bpre[2 * q], b1 = bpre[2 * q + 1];
                float v0 = fmaxf(a0.x + b0.x, 0.0f), v1 = fmaxf(a0.y + b0.y, 0.0f);
                float v2 = fmaxf(a0.z + b0.z, 0.0f), v3 = fmaxf(a0.w + b0.w, 0.0f);
                float v4 = fmaxf(a1.x + b1.x, 0.0f), v5 = fmaxf(a1.y + b1.y, 0.0f);
                float v6 = fmaxf(a1.z + b1.z, 0.0f), v7 = fmaxf(a1.w + b1.w, 0.0f);
                uint4 H, L;
                split_pack2(v0, v1, H.x, L.x);
                split_pack2(v2, v3, H.y, L.y);
                split_pack2(v4, v5, H.z, L.z);
                split_pack2(v6, v7, H.w, L.w);
                *(uint4*)(aHi + base + q * 128) = H;
                *(uint4*)(aLo + base + q * 128) = L;
            }
        }
        __syncthreads();

        // issue next group's gather NOW; lands during the MFMA phase below
        if (it < 3) {
            const int c = col[(node0 + 4) * KNB + row];
            const float* br = B3 + (size_t)c * 128 + kcm * 32;
#pragma unroll
            for (int q = 0; q < 4; ++q) {
                bpre[2 * q]     = *(const float4*)(br + q * 8);
                bpre[2 * q + 1] = *(const float4*)(br + q * 8 + 4);
            }
        }

        // MFMA phase: wave wv owns n-tiles {2wv, 2wv+1} x all 4 m-tiles
        floatx4 acc[4][2];
#pragma unroll
        for (int mt = 0; mt < 4; ++mt)
#pragma unroll
            for (int ntl = 0; ntl < 2; ++ntl)
                acc[mt][ntl] = (floatx4){0.0f, 0.0f, 0.0f, 0.0f};

#pragma unroll
        for (int kc = 0; kc < 4; ++kc) {
            bf16x8 bh[2], bl[2];
#pragma unroll
            for (int ntl = 0; ntl < 2; ++ntl) {
                int nt = ntb + ntl;
                bh[ntl] = __builtin_bit_cast(bf16x8,
                    *(const uint4*)(WH + (size_t)((kc * 8 + nt) * 64 + lane) * 8));
                bl[ntl] = __builtin_bit_cast(bf16x8,
                    *(const uint4*)(WL + (size_t)((kc * 8 + nt) * 64 + lane) * 8));
            }
            bf16x8 ah[4], al[4];
#pragma unroll
            for (int mt = 0; mt < 4; ++mt) {
                ah[mt] = __builtin_bit_cast(bf16x8,
                    *(const uint4*)(aHi + (mt * 4 + kc) * 512 + lane * 8));
                al[mt] = __builtin_bit_cast(bf16x8,
                    *(const uint4*)(aLo + (mt * 4 + kc) * 512 + lane * 8));
            }
#pragma unroll
            for (int mt = 0; mt < 4; ++mt)
#pragma unroll
                for (int ntl = 0; ntl < 2; ++ntl) {
                    acc[mt][ntl] = __builtin_amdgcn_mfma_f32_16x16x32_bf16(
                        ah[mt], bh[ntl], acc[mt][ntl], 0, 0, 0);
                    acc[mt][ntl] = __builtin_amdgcn_mfma_f32_16x16x32_bf16(
                        ah[mt], bl[ntl], acc[mt][ntl], 0, 0, 0);
                    acc[mt][ntl] = __builtin_amdgcn_mfma_f32_16x16x32_bf16(
                        al[mt], bh[ntl], acc[mt][ntl], 0, 0, 0);
                }
        }

        // K-max in-register + g store. D layout: row=(lane>>4)*4+reg, col=lane&15.
#pragma unroll
        for (int mt = 0; mt < 4; ++mt)
#pragma unroll
            for (int ntl = 0; ntl < 2; ++ntl) {
                floatx4 a = acc[mt][ntl];
                float mm = fmaxf(fmaxf(a[0], a[1]), fmaxf(a[2], a[3]));
                mm = fmaxf(mm, __shfl_xor(mm, 16));
                mm = fmaxf(mm, __shfl_xor(mm, 32));
                if (lane < 16) {
                    int ccol = (ntb + ntl) * 16 + lane;
                    g[(size_t)(node0 + mt) * 128 + ccol] =
                        fmaxf(mm + b4[ccol], 0.0f);
                }
            }
        __syncthreads();   // all MFMA reads of aHi/aLo done before next overwrite
    }
}

// ---------------- K4 (MFMA): 64 nodes/block; out = relu(g@W5+b5)@W6+b6 --------
__global__ __launch_bounds__(256) void k4_kernel(
    const float* __restrict__ g,
    const unsigned short* __restrict__ WH, const unsigned short* __restrict__ WL,
    const float* __restrict__ b5, const float* __restrict__ b6,
    float* __restrict__ out)
{
    __shared__ __align__(16) float gF[16 * 512];   // 32 KB, frag-contig fp32
    const int t = threadIdx.x;
    const int n0 = blockIdx.x * 64;

    // phase A: stage g rows into frag layout (clamp tail)
    {
        const int row = t & 63, part = t >> 6;    // part == kc
        int gn = n0 + row; if (gn >= NN) gn = NN - 1;
        const float* gr = g + (size_t)gn * 128 + part * 32;
        int mt = row >> 4, m = row & 15;
        float* base = gF + (mt * 4 + part) * 512 + m * 8;
#pragma unroll
        for (int qq = 0; qq < 4; ++qq) {
            *(float4*)(base + qq * 128)     = *(const float4*)(gr + qq * 8);
            *(float4*)(base + qq * 128 + 4) = *(const float4*)(gr + qq * 8 + 4);
        }
    }
    __syncthreads();

    const int w = __builtin_amdgcn_readfirstlane(t >> 6);
    const int lane = t & 63;

    // GEMM1: t1-tile rows w*16..+15; acc1[nt=0..7]
    floatx4 acc1[8];
#pragma unroll
    for (int nt = 0; nt < 8; ++nt) acc1[nt] = (floatx4){0.f, 0.f, 0.f, 0.f};
#pragma unroll
    for (int kc = 0; kc < 4; ++kc) {
        const float* ap = gF + (w * 4 + kc) * 512 + lane * 8;
        bf16x8 ah, al;
        split8(*(const float4*)ap, *(const float4*)(ap + 4), ah, al);
#pragma unroll
        for (int nt = 0; nt < 8; ++nt) {
            size_t fb = (size_t)(W5F + kc * 8 + nt) * 512 + lane * 8;
            bf16x8 bh = __builtin_bit_cast(bf16x8, *(const uint4*)(WH + fb));
            bf16x8 bl = __builtin_bit_cast(bf16x8, *(const uint4*)(WL + fb));
            acc1[nt] = __builtin_amdgcn_mfma_f32_16x16x32_bf16(ah, bh, acc1[nt], 0, 0, 0);
            acc1[nt] = __builtin_amdgcn_mfma_f32_16x16x32_bf16(ah, bl, acc1[nt], 0, 0, 0);
            acc1[nt] = __builtin_amdgcn_mfma_f32_16x16x32_bf16(al, bh, acc1[nt], 0, 0, 0);
        }
    }
    // t1 = relu(acc1 + b5) -> overwrite own frags (wave-local, reads done)
    {
        const int qq = lane >> 4, cc = lane & 15;
#pragma unroll
        for (int nt = 0; nt < 8; ++nt) {
            float bv = b5[nt * 16 + cc];
            int colIdx = nt * 16 + cc;
            int kc2 = colIdx >> 5, q2 = (colIdx >> 3) & 3, jj = cc & 7;
            float* dst = gF + (w * 4 + kc2) * 512 + q2 * 128 + jj;
#pragma unroll
            for (int r = 0; r < 4; ++r)
                dst[(qq * 4 + r) * 8] = fmaxf(acc1[nt][r] + bv, 0.0f);
        }
    }
    // GEMM2: [16 x 128] @ W6pad[128 x 48]; acc2[nt=0..2]
    floatx4 acc2[3];
#pragma unroll
    for (int nt = 0; nt < 3; ++nt) acc2[nt] = (floatx4){0.f, 0.f, 0.f, 0.f};
#pragma unroll
    for (int kc = 0; kc < 4; ++kc) {
        const float* ap = gF + (w * 4 + kc) * 512 + lane * 8;
        bf16x8 ah, al;
        split8(*(const float4*)ap, *(const float4*)(ap + 4), ah, al);
#pragma unroll
        for (int nt = 0; nt < 3; ++nt) {
            size_t fb = (size_t)(W6F + kc * 3 + nt) * 512 + lane * 8;
            bf16x8 bh = __builtin_bit_cast(bf16x8, *(const uint4*)(WH + fb));
            bf16x8 bl = __builtin_bit_cast(bf16x8, *(const uint4*)(WL + fb));
            acc2[nt] = __builtin_amdgcn_mfma_f32_16x16x32_bf16(ah, bh, acc2[nt], 0, 0, 0);
            acc2[nt] = __builtin_amdgcn_mfma_f32_16x16x32_bf16(ah, bl, acc2[nt], 0, 0, 0);
            acc2[nt] = __builtin_amdgcn_mfma_f32_16x16x32_bf16(al, bh, acc2[nt], 0, 0, 0);
        }
    }
    // store out (cols >= 40 are pad)
    {
        const int qq = lane >> 4, cc = lane & 15;
#pragma unroll
        for (int nt = 0; nt < 3; ++nt) {
            int n = nt * 16 + cc;
            if (n < 40) {
                float bv = b6[n];
#pragma unroll
                for (int r = 0; r < 4; ++r) {
                    int i = n0 + w * 16 + qq * 4 + r;
                    if (i < NN)
                        out[(size_t)i * 40 + n] = acc2[nt][r] + bv;
                }
            }
        }
    }
}

extern "C" void kernel_launch(void* const* d_in, const int* in_sizes, int n_in,
                              void* d_out, int out_size, void* d_ws, size_t ws_size,
                              hipStream_t stream)
{
    const float* x  = (const float*)d_in[0];
    const int* ei   = (const int*)d_in[1];
    const int* col  = ei + EE;
    const float* W1 = (const float*)d_in[2];
    const float* b1 = (const float*)d_in[3];
    const float* W2 = (const float*)d_in[4];
    const float* b2 = (const float*)d_in[5];
    const float* W3 = (const float*)d_in[6];
    const float* b3 = (const float*)d_in[7];
    const float* W4 = (const float*)d_in[8];
    const float* b4 = (const float*)d_in[9];
    const float* W5 = (const float*)d_in[10];
    const float* b5 = (const float*)d_in[11];
    const float* W6 = (const float*)d_in[12];
    const float* b6 = (const float*)d_in[13];
    float* out = (float*)d_out;

    float* A1 = (float*)d_ws;                    // [N,64]
    float* B1 = A1 + (size_t)NN * 64;            // [N,64]
    float* A3 = B1 + (size_t)NN * 64;            // [N,128]
    float* B3 = A3 + (size_t)NN * 128;           // [N,128]
    unsigned short* WH = (unsigned short*)(B3 + (size_t)NN * 128);  // [116*512]
    unsigned short* WL = WH + NFRAG * 512;
    float* g  = A1;                              // [N,128] reuses A1/B1 (dead after k2)

    kw_kernel<<<(NFRAG * 64 + 255) / 256, 256, 0, stream>>>(W2, W3, W4, W5, W6, WH, WL);
    k1_kernel<<<NN * 64 / 256, 256, 0, stream>>>(x, W1, b1, A1, B1);
    k2_kernel<<<(NN + 63) / 64, 256, 0, stream>>>(col, A1, B1, WH, WL, b2, b3, A3, B3);
    k3_kernel<<<NN / 16, 256, 0, stream>>>(col, A3, B3,
                                           WH + (size_t)W4F * 512, WL + (size_t)W4F * 512,
                                           b4, g);
    k4_kernel<<<(NN + 63) / 64, 256, 0, stream>>>(g, WH, WL, b5, b6, out);
}

// Round 10
// 455.853 us; speedup vs baseline: 1.3977x; 1.0259x over previous
//
#include <hip/hip_runtime.h>

// DGCNN on MI355X — round 10: barrier-free k3 with weights+A3 staged in LDS.
// R9 post-mortem: bulk-sync barriers cap k3 at ~248us (18.6k cyc/group-step vs
// ~3k of work). New k3: one staging barrier (W4 hi/lo 64KB + block A3 8KB into
// LDS), then each wave independently does 4 nodes as 2 pairs: per-lane
// self-gather of its exact A-frag (R7-verified partition), split in-register,
// MFMA with ds_read weight frags (2 reads per 6 MFMAs). Pair-1 gather issued
// before pair-0 MFMA. 2 blocks/CU but self-paced waves (no barrier coupling).
//   concat(a, b-a) @ W + bias = a @ (Wt-Wb) + b @ Wb + bias
//   conv2 gathers h1 with NODE ids -> only h1[0:N] rows needed

#define NN 100000
#define KNB 16
#define EE (NN * KNB)

// weight fragment bases (units of 512 ushorts = one 64-lane x 8-bf16 frag)
#define W2F 0     // W2  [64][64]   : 2 kc x 4 nt  = 8
#define W3F 8     // W3X [64][256]  : 2 kc x 16 nt = 32  (cols 0-127: W3t-W3b, 128-255: W3b)
#define W4F 40    // W4  [128][128] : 4 kc x 8 nt  = 32
#define W5F 72    // W5  [128][128] : 4 kc x 8 nt  = 32
#define W6F 104   // W6  [128][48p] : 4 kc x 3 nt  = 12
#define NFRAG 116

typedef float floatx4 __attribute__((ext_vector_type(4)));
typedef __bf16 bf16x8 __attribute__((ext_vector_type(8)));

static __device__ __forceinline__ unsigned f2bf_rne_u(float f) {
    unsigned u = __float_as_uint(f);
    return (u + 0x7FFFu + ((u >> 16) & 1u)) >> 16;
}
static __device__ __forceinline__ float bfu2f(unsigned h) {
    return __uint_as_float(h << 16);
}

// split a pair of fp32 into packed bf16 hi (truncate) + bf16 lo (RNE of exact
// residual). hp = {lo16: a_hi, hi16: b_hi}; one v_perm_b32 per pack.
static __device__ __forceinline__ void split_pack2(float a, float b,
                                                   unsigned& hp, unsigned& lp) {
    unsigned ua = __float_as_uint(a), ub = __float_as_uint(b);
    hp = __builtin_amdgcn_perm(ub, ua, 0x07060302u);        // [b.b3 b.b2 a.b3 a.b2]
    float ra = a - __uint_as_float(ua & 0xFFFF0000u);       // exact residual
    float rb = b - __uint_as_float(ub & 0xFFFF0000u);
    unsigned la = __float_as_uint(ra), lb = __float_as_uint(rb);
    la = la + 0x7FFFu + ((la >> 16) & 1u);                  // RNE round point
    lb = lb + 0x7FFFu + ((lb >> 16) & 1u);
    lp = __builtin_amdgcn_perm(lb, la, 0x07060302u);
}

// split 8 fp32 -> bf16x8 hi + bf16x8 lo
static __device__ __forceinline__ void split8(float4 f0, float4 f1,
                                              bf16x8& ah, bf16x8& al) {
    unsigned hd[4], ld[4];
    split_pack2(f0.x, f0.y, hd[0], ld[0]);
    split_pack2(f0.z, f0.w, hd[1], ld[1]);
    split_pack2(f1.x, f1.y, hd[2], ld[2]);
    split_pack2(f1.z, f1.w, hd[3], ld[3]);
    uint4 H = {hd[0], hd[1], hd[2], hd[3]};
    uint4 L = {ld[0], ld[1], ld[2], ld[3]};
    ah = __builtin_bit_cast(bf16x8, H);
    al = __builtin_bit_cast(bf16x8, L);
}

// ---------------- KW: pre-split all weights into frag-ordered bf16 hi/lo ------
// Frag (kc,nt): lane l holds W[kc*32 + (l>>4)*8 + j][nt*16 + (l&15)], j=0..7.
__global__ __launch_bounds__(256) void kw_kernel(
    const float* __restrict__ W2, const float* __restrict__ W3,
    const float* __restrict__ W4, const float* __restrict__ W5,
    const float* __restrict__ W6,
    unsigned short* __restrict__ WH, unsigned short* __restrict__ WL)
{
    int d = blockIdx.x * 256 + threadIdx.x;
    if (d >= NFRAG * 64) return;
    int f = d >> 6, l = d & 63, c = l & 15, q = l >> 4;
    float v[8];
    if (f < W3F) {                    // W2 [64][64]
        int fx = f - W2F, kc = fx >> 2, nt = fx & 3;
        int k0 = kc * 32 + q * 8, n = nt * 16 + c;
#pragma unroll
        for (int j = 0; j < 8; ++j) v[j] = W2[(k0 + j) * 64 + n];
    } else if (f < W4F) {             // W3X [64][256]
        int fx = f - W3F, kc = fx >> 4, nt = fx & 15;
        int k0 = kc * 32 + q * 8, n = nt * 16 + c;
#pragma unroll
        for (int j = 0; j < 8; ++j) {
            int k = k0 + j;
            v[j] = (n < 128) ? (W3[k * 128 + n] - W3[(64 + k) * 128 + n])
                             : W3[(64 + k) * 128 + (n - 128)];
        }
    } else if (f < W5F) {             // W4 [128][128]
        int fx = f - W4F, kc = fx >> 3, nt = fx & 7;
        int k0 = kc * 32 + q * 8, n = nt * 16 + c;
#pragma unroll
        for (int j = 0; j < 8; ++j) v[j] = W4[(k0 + j) * 128 + n];
    } else if (f < W6F) {             // W5 [128][128]
        int fx = f - W5F, kc = fx >> 3, nt = fx & 7;
        int k0 = kc * 32 + q * 8, n = nt * 16 + c;
#pragma unroll
        for (int j = 0; j < 8; ++j) v[j] = W5[(k0 + j) * 128 + n];
    } else {                          // W6 [128][40] padded to 48
        int fx = f - W6F, kc = fx / 3, nt = fx % 3;
        int k0 = kc * 32 + q * 8, n = nt * 16 + c;
#pragma unroll
        for (int j = 0; j < 8; ++j)
            v[j] = (n < 40) ? W6[(k0 + j) * 40 + n] : 0.0f;
    }
    unsigned hs[8], ls[8];
#pragma unroll
    for (int j = 0; j < 8; ++j) {
        unsigned h = f2bf_rne_u(v[j]);
        float r = v[j] - bfu2f(h);
        hs[j] = h;
        ls[j] = f2bf_rne_u(r);
    }
    uint4 H, L;
    H.x = hs[0] | (hs[1] << 16); H.y = hs[2] | (hs[3] << 16);
    H.z = hs[4] | (hs[5] << 16); H.w = hs[6] | (hs[7] << 16);
    L.x = ls[0] | (ls[1] << 16); L.y = ls[2] | (ls[3] << 16);
    L.z = ls[4] | (ls[5] << 16); L.w = ls[6] | (ls[7] << 16);
    *(uint4*)(WH + (size_t)d * 8) = H;
    *(uint4*)(WL + (size_t)d * 8) = L;
}

// ---------------- K1: A1 = x@(W1t-W1b)+b1, B1 = x@W1b ----------------
__global__ __launch_bounds__(256) void k1_kernel(
    const float* __restrict__ x, const float* __restrict__ W1,
    const float* __restrict__ b1, float* __restrict__ A1, float* __restrict__ B1)
{
    int gid = blockIdx.x * 256 + threadIdx.x;
    int n = gid >> 6;
    int j = gid & 63;
    const float* xr = x + n * 16;
    float acc_a = b1[j];
    float acc_b = 0.0f;
#pragma unroll
    for (int k = 0; k < 16; ++k) {
        float xv = xr[k];
        float wt = W1[k * 64 + j];
        float wb = W1[(16 + k) * 64 + j];
        acc_a = fmaf(xv, wt - wb, acc_a);
        acc_b = fmaf(xv, wb, acc_b);
    }
    A1[n * 64 + j] = acc_a;
    B1[n * 64 + j] = acc_b;
}

// ---------------- K2 (MFMA, R6 version): 64 rows/block --------------------
__global__ __launch_bounds__(256) void k2_kernel(
    const int* __restrict__ col,
    const float* __restrict__ A1, const float* __restrict__ B1,
    const unsigned short* __restrict__ WH, const unsigned short* __restrict__ WL,
    const float* __restrict__ b2, const float* __restrict__ b3,
    float* __restrict__ A3, float* __restrict__ B3)
{
    __shared__ __align__(16) float tF[8 * 512];   // 16 KB, frag-contig fp32
    __shared__ __align__(16) float hF[8 * 512];   // 16 KB
    const int t = threadIdx.x;
    const int i0 = blockIdx.x * 64;

    // phase A: t[row] = relu(A1[i>>4] + B1[col[i]]) -> tF frag layout
    {
        const int row = t & 63, part = t >> 6;
        int i = i0 + row;                 // tail reads valid (i < EE), stores guarded
        int nn = i >> 4;
        int ci = col[i];
        const float* ar = A1 + (size_t)nn * 64 + part * 16;
        const float* br = B1 + (size_t)ci * 64 + part * 16;
        int mt = row >> 4, m = row & 15, kc = part >> 1;
        float* base = tF + (mt * 2 + kc) * 512 + m * 8;
#pragma unroll
        for (int h = 0; h < 2; ++h) {
            int qq = (part & 1) * 2 + h;
            float4 a0 = *(const float4*)(ar + h * 8);
            float4 b0 = *(const float4*)(br + h * 8);
            float4 a1 = *(const float4*)(ar + h * 8 + 4);
            float4 b1v = *(const float4*)(br + h * 8 + 4);
            float4 r0, r1;
            r0.x = fmaxf(a0.x + b0.x, 0.0f); r0.y = fmaxf(a0.y + b0.y, 0.0f);
            r0.z = fmaxf(a0.z + b0.z, 0.0f); r0.w = fmaxf(a0.w + b0.w, 0.0f);
            r1.x = fmaxf(a1.x + b1v.x, 0.0f); r1.y = fmaxf(a1.y + b1v.y, 0.0f);
            r1.z = fmaxf(a1.z + b1v.z, 0.0f); r1.w = fmaxf(a1.w + b1v.w, 0.0f);
            *(float4*)(base + qq * 128) = r0;
            *(float4*)(base + qq * 128 + 4) = r1;
        }
    }
    __syncthreads();

    const int w = __builtin_amdgcn_readfirstlane(t >> 6);   // wave = m-tile
    const int lane = t & 63;

    // GEMM1: h-tile rows w*16..+15; acc1[nt=0..3]
    floatx4 acc1[4];
#pragma unroll
    for (int nt = 0; nt < 4; ++nt) acc1[nt] = (floatx4){0.f, 0.f, 0.f, 0.f};
#pragma unroll
    for (int kc = 0; kc < 2; ++kc) {
        const float* ap = tF + (w * 2 + kc) * 512 + lane * 8;
        bf16x8 ah, al;
        split8(*(const float4*)ap, *(const float4*)(ap + 4), ah, al);
#pragma unroll
        for (int nt = 0; nt < 4; ++nt) {
            size_t fb = (size_t)(W2F + kc * 4 + nt) * 512 + lane * 8;
            bf16x8 bh = __builtin_bit_cast(bf16x8, *(const uint4*)(WH + fb));
            bf16x8 bl = __builtin_bit_cast(bf16x8, *(const uint4*)(WL + fb));
            acc1[nt] = __builtin_amdgcn_mfma_f32_16x16x32_bf16(ah, bh, acc1[nt], 0, 0, 0);
            acc1[nt] = __builtin_amdgcn_mfma_f32_16x16x32_bf16(ah, bl, acc1[nt], 0, 0, 0);
            acc1[nt] = __builtin_amdgcn_mfma_f32_16x16x32_bf16(al, bh, acc1[nt], 0, 0, 0);
        }
    }
    // h = relu(acc1 + b2) -> hF frag layout (wave-local rows -> no barrier)
    {
        const int qq = lane >> 4, cc = lane & 15;
#pragma unroll
        for (int nt = 0; nt < 4; ++nt) {
            float bv = b2[nt * 16 + cc];
            int colIdx = nt * 16 + cc;
            int kc2 = colIdx >> 5, q2 = (colIdx >> 3) & 3, jj = cc & 7;
            float* dst = hF + (w * 2 + kc2) * 512 + q2 * 128 + jj;
#pragma unroll
            for (int r = 0; r < 4; ++r)
                dst[(qq * 4 + r) * 8] = fmaxf(acc1[nt][r] + bv, 0.0f);
        }
    }
    // GEMM2: [16 x 64] @ W3X[64 x 256]; acc2[nt=0..15]
    floatx4 acc2[16];
#pragma unroll
    for (int nt = 0; nt < 16; ++nt) acc2[nt] = (floatx4){0.f, 0.f, 0.f, 0.f};
#pragma unroll
    for (int kc = 0; kc < 2; ++kc) {
        const float* ap = hF + (w * 2 + kc) * 512 + lane * 8;
        bf16x8 ah, al;
        split8(*(const float4*)ap, *(const float4*)(ap + 4), ah, al);
#pragma unroll
        for (int nt = 0; nt < 16; ++nt) {
            size_t fb = (size_t)(W3F + kc * 16 + nt) * 512 + lane * 8;
            bf16x8 bh = __builtin_bit_cast(bf16x8, *(const uint4*)(WH + fb));
            bf16x8 bl = __builtin_bit_cast(bf16x8, *(const uint4*)(WL + fb));
            acc2[nt] = __builtin_amdgcn_mfma_f32_16x16x32_bf16(ah, bh, acc2[nt], 0, 0, 0);
            acc2[nt] = __builtin_amdgcn_mfma_f32_16x16x32_bf16(ah, bl, acc2[nt], 0, 0, 0);
            acc2[nt] = __builtin_amdgcn_mfma_f32_16x16x32_bf16(al, bh, acc2[nt], 0, 0, 0);
        }
    }
    // store: cols 0-127 -> A3 (+b3), 128-255 -> B3
    {
        const int qq = lane >> 4, cc = lane & 15;
#pragma unroll
        for (int nt = 0; nt < 16; ++nt) {
            int n = nt * 16 + cc;
            float bv = (n < 128) ? b3[n] : 0.0f;
#pragma unroll
            for (int r = 0; r < 4; ++r) {
                int i = i0 + w * 16 + qq * 4 + r;
                if (i < NN) {
                    float vv = acc2[nt][r];
                    if (n < 128) A3[(size_t)i * 128 + n] = vv + bv;
                    else         B3[(size_t)i * 128 + (n - 128)] = vv;
                }
            }
        }
    }
}

// ---------------- K3: barrier-free after staging. Block = 16 nodes, 4 waves.
// LDS: W4 hi/lo frags (64 KB) + block A3 rows (8 KB). Wave w owns nodes
// w*4..w*4+3 as 2 pairs; lane self-gathers its A-frag, weights via ds_read.
__global__ __launch_bounds__(256, 2) void k3_kernel(
    const int* __restrict__ col,
    const float* __restrict__ A3, const float* __restrict__ B3,
    const unsigned short* __restrict__ WH, const unsigned short* __restrict__ WL,
    const float* __restrict__ b4, float* __restrict__ g)
{
    __shared__ __align__(16) unsigned short wlds[32768];  // 64 KB: H then L
    __shared__ __align__(16) float ashare[2048];          // 8 KB: 16 A3 rows
    const int t = threadIdx.x;
    const int lane = t & 63;
    const int w = t >> 6;
    const int m = lane & 15, q = lane >> 4;
    const int nodeB = blockIdx.x * 16;
    const int node0 = nodeB + w * 4;

    // prefetch pair0's B3 gather (issued before staging so it's in flight)
    float4 braw[16];
#pragma unroll
    for (int ng = 0; ng < 2; ++ng) {
        const int c = col[(node0 + ng) * KNB + m];
        const float* br = B3 + (size_t)c * 128 + q * 8;
#pragma unroll
        for (int kc = 0; kc < 4; ++kc) {
            braw[ng * 8 + kc * 2]     = *(const float4*)(br + kc * 32);
            braw[ng * 8 + kc * 2 + 1] = *(const float4*)(br + kc * 32 + 4);
        }
    }
    // stage A3 rows (8 KB) and W4 hi/lo frags (64 KB), coalesced
    {
        const float4* asrc = (const float4*)(A3 + (size_t)nodeB * 128);
        float4* adst = (float4*)ashare;
        adst[t]       = asrc[t];
        adst[t + 256] = asrc[t + 256];
        const uint4* hsrc = (const uint4*)WH;
        const uint4* lsrc = (const uint4*)WL;
        uint4* wdst = (uint4*)wlds;
#pragma unroll
        for (int i = 0; i < 8; ++i) wdst[t + i * 256]        = hsrc[t + i * 256];
#pragma unroll
        for (int i = 0; i < 8; ++i) wdst[2048 + t + i * 256] = lsrc[t + i * 256];
    }
    __syncthreads();   // the only block-wide barrier

#pragma unroll
    for (int p = 0; p < 2; ++p) {
        // split current pair: lane's A-frag = relu(A3[node]+B3[col]) hi/lo
        bf16x8 aH[2][4], aL[2][4];
#pragma unroll
        for (int ng = 0; ng < 2; ++ng) {
            const float* ar = ashare + (w * 4 + p * 2 + ng) * 128 + q * 8;
#pragma unroll
            for (int kc = 0; kc < 4; ++kc) {
                float4 b0 = braw[ng * 8 + kc * 2];
                float4 b1 = braw[ng * 8 + kc * 2 + 1];
                float4 a0 = *(const float4*)(ar + kc * 32);
                float4 a1 = *(const float4*)(ar + kc * 32 + 4);
                float v0 = fmaxf(a0.x + b0.x, 0.0f), v1 = fmaxf(a0.y + b0.y, 0.0f);
                float v2 = fmaxf(a0.z + b0.z, 0.0f), v3 = fmaxf(a0.w + b0.w, 0.0f);
                float v4 = fmaxf(a1.x + b1.x, 0.0f), v5 = fmaxf(a1.y + b1.y, 0.0f);
                float v6 = fmaxf(a1.z + b1.z, 0.0f), v7 = fmaxf(a1.w + b1.w, 0.0f);
                uint4 H, L;
                split_pack2(v0, v1, H.x, L.x);
                split_pack2(v2, v3, H.y, L.y);
                split_pack2(v4, v5, H.z, L.z);
                split_pack2(v6, v7, H.w, L.w);
                aH[ng][kc] = __builtin_bit_cast(bf16x8, H);
                aL[ng][kc] = __builtin_bit_cast(bf16x8, L);
            }
        }
        // issue next pair's gather NOW; lands during this pair's MFMA phase
        if (p == 0) {
#pragma unroll
            for (int ng = 0; ng < 2; ++ng) {
                const int c = col[(node0 + 2 + ng) * KNB + m];
                const float* br = B3 + (size_t)c * 128 + q * 8;
#pragma unroll
                for (int kc = 0; kc < 4; ++kc) {
                    braw[ng * 8 + kc * 2]     = *(const float4*)(br + kc * 32);
                    braw[ng * 8 + kc * 2 + 1] = *(const float4*)(br + kc * 32 + 4);
                }
            }
        }
        // MFMA: all 8 n-tiles for both nodes; bh/bl amortized over 6 MFMAs
        floatx4 acc[2][8];
#pragma unroll
        for (int ng = 0; ng < 2; ++ng)
#pragma unroll
            for (int nt = 0; nt < 8; ++nt)
                acc[ng][nt] = (floatx4){0.0f, 0.0f, 0.0f, 0.0f};
#pragma unroll
        for (int kc = 0; kc < 4; ++kc) {
#pragma unroll
            for (int nt = 0; nt < 8; ++nt) {
                const int f = kc * 8 + nt;
                bf16x8 bh = __builtin_bit_cast(bf16x8,
                    *(const uint4*)(wlds + f * 512 + lane * 8));
                bf16x8 bl = __builtin_bit_cast(bf16x8,
                    *(const uint4*)(wlds + 16384 + f * 512 + lane * 8));
#pragma unroll
                for (int ng = 0; ng < 2; ++ng) {
                    acc[ng][nt] = __builtin_amdgcn_mfma_f32_16x16x32_bf16(
                        aH[ng][kc], bh, acc[ng][nt], 0, 0, 0);
                    acc[ng][nt] = __builtin_amdgcn_mfma_f32_16x16x32_bf16(
                        aH[ng][kc], bl, acc[ng][nt], 0, 0, 0);
                    acc[ng][nt] = __builtin_amdgcn_mfma_f32_16x16x32_bf16(
                        aL[ng][kc], bh, acc[ng][nt], 0, 0, 0);
                }
            }
        }
        // K-max in-register (rows = the node's 16 edges), store g
#pragma unroll
        for (int ng = 0; ng < 2; ++ng) {
            const int node = node0 + p * 2 + ng;
#pragma unroll
            for (int nt = 0; nt < 8; ++nt) {
                floatx4 a = acc[ng][nt];
                float mm = fmaxf(fmaxf(a[0], a[1]), fmaxf(a[2], a[3]));
                mm = fmaxf(mm, __shfl_xor(mm, 16));
                mm = fmaxf(mm, __shfl_xor(mm, 32));
                if (lane < 16) {
                    int ccol = nt * 16 + lane;
                    g[(size_t)node * 128 + ccol] = fmaxf(mm + b4[ccol], 0.0f);
                }
            }
        }
    }
}

// ---------------- K4 (MFMA): 64 nodes/block; out = relu(g@W5+b5)@W6+b6 --------
__global__ __launch_bounds__(256) void k4_kernel(
    const float* __restrict__ g,
    const unsigned short* __restrict__ WH, const unsigned short* __restrict__ WL,
    const float* __restrict__ b5, const float* __restrict__ b6,
    float* __restrict__ out)
{
    __shared__ __align__(16) float gF[16 * 512];   // 32 KB, frag-contig fp32
    const int t = threadIdx.x;
    const int n0 = blockIdx.x * 64;

    // phase A: stage g rows into frag layout (clamp tail)
    {
        const int row = t & 63, part = t >> 6;    // part == kc
        int gn = n0 + row; if (gn >= NN) gn = NN - 1;
        const float* gr = g + (size_t)gn * 128 + part * 32;
        int mt = row >> 4, m = row & 15;
        float* base = gF + (mt * 4 + part) * 512 + m * 8;
#pragma unroll
        for (int qq = 0; qq < 4; ++qq) {
            *(float4*)(base + qq * 128)     = *(const float4*)(gr + qq * 8);
            *(float4*)(base + qq * 128 + 4) = *(const float4*)(gr + qq * 8 + 4);
        }
    }
    __syncthreads();

    const int w = __builtin_amdgcn_readfirstlane(t >> 6);
    const int lane = t & 63;

    // GEMM1: t1-tile rows w*16..+15; acc1[nt=0..7]
    floatx4 acc1[8];
#pragma unroll
    for (int nt = 0; nt < 8; ++nt) acc1[nt] = (floatx4){0.f, 0.f, 0.f, 0.f};
#pragma unroll
    for (int kc = 0; kc < 4; ++kc) {
        const float* ap = gF + (w * 4 + kc) * 512 + lane * 8;
        bf16x8 ah, al;
        split8(*(const float4*)ap, *(const float4*)(ap + 4), ah, al);
#pragma unroll
        for (int nt = 0; nt < 8; ++nt) {
            size_t fb = (size_t)(W5F + kc * 8 + nt) * 512 + lane * 8;
            bf16x8 bh = __builtin_bit_cast(bf16x8, *(const uint4*)(WH + fb));
            bf16x8 bl = __builtin_bit_cast(bf16x8, *(const uint4*)(WL + fb));
            acc1[nt] = __builtin_amdgcn_mfma_f32_16x16x32_bf16(ah, bh, acc1[nt], 0, 0, 0);
            acc1[nt] = __builtin_amdgcn_mfma_f32_16x16x32_bf16(ah, bl, acc1[nt], 0, 0, 0);
            acc1[nt] = __builtin_amdgcn_mfma_f32_16x16x32_bf16(al, bh, acc1[nt], 0, 0, 0);
        }
    }
    // t1 = relu(acc1 + b5) -> overwrite own frags (wave-local, reads done)
    {
        const int qq = lane >> 4, cc = lane & 15;
#pragma unroll
        for (int nt = 0; nt < 8; ++nt) {
            float bv = b5[nt * 16 + cc];
            int colIdx = nt * 16 + cc;
            int kc2 = colIdx >> 5, q2 = (colIdx >> 3) & 3, jj = cc & 7;
            float* dst = gF + (w * 4 + kc2) * 512 + q2 * 128 + jj;
#pragma unroll
            for (int r = 0; r < 4; ++r)
                dst[(qq * 4 + r) * 8] = fmaxf(acc1[nt][r] + bv, 0.0f);
        }
    }
    // GEMM2: [16 x 128] @ W6pad[128 x 48]; acc2[nt=0..2]
    floatx4 acc2[3];
#pragma unroll
    for (int nt = 0; nt < 3; ++nt) acc2[nt] = (floatx4){0.f, 0.f, 0.f, 0.f};
#pragma unroll
    for (int kc = 0; kc < 4; ++kc) {
        const float* ap = gF + (w * 4 + kc) * 512 + lane * 8;
        bf16x8 ah, al;
        split8(*(const float4*)ap, *(const float4*)(ap + 4), ah, al);
#pragma unroll
        for (int nt = 0; nt < 3; ++nt) {
            size_t fb = (size_t)(W6F + kc * 3 + nt) * 512 + lane * 8;
            bf16x8 bh = __builtin_bit_cast(bf16x8, *(const uint4*)(WH + fb));
            bf16x8 bl = __builtin_bit_cast(bf16x8, *(const uint4*)(WL + fb));
            acc2[nt] = __builtin_amdgcn_mfma_f32_16x16x32_bf16(ah, bh, acc2[nt], 0, 0, 0);
            acc2[nt] = __builtin_amdgcn_mfma_f32_16x16x32_bf16(ah, bl, acc2[nt], 0, 0, 0);
            acc2[nt] = __builtin_amdgcn_mfma_f32_16x16x32_bf16(al, bh, acc2[nt], 0, 0, 0);
        }
    }
    // store out (cols >= 40 are pad)
    {
        const int qq = lane >> 4, cc = lane & 15;
#pragma unroll
        for (int nt = 0; nt < 3; ++nt) {
            int n = nt * 16 + cc;
            if (n < 40) {
                float bv = b6[n];
#pragma unroll
                for (int r = 0; r < 4; ++r) {
                    int i = n0 + w * 16 + qq * 4 + r;
                    if (i < NN)
                        out[(size_t)i * 40 + n] = acc2[nt][r] + bv;
                }
            }
        }
    }
}

extern "C" void kernel_launch(void* const* d_in, const int* in_sizes, int n_in,
                              void* d_out, int out_size, void* d_ws, size_t ws_size,
                              hipStream_t stream)
{
    const float* x  = (const float*)d_in[0];
    const int* ei   = (const int*)d_in[1];
    const int* col  = ei + EE;
    const float* W1 = (const float*)d_in[2];
    const float* b1 = (const float*)d_in[3];
    const float* W2 = (const float*)d_in[4];
    const float* b2 = (const float*)d_in[5];
    const float* W3 = (const float*)d_in[6];
    const float* b3 = (const float*)d_in[7];
    const float* W4 = (const float*)d_in[8];
    const float* b4 = (const float*)d_in[9];
    const float* W5 = (const float*)d_in[10];
    const float* b5 = (const float*)d_in[11];
    const float* W6 = (const float*)d_in[12];
    const float* b6 = (const float*)d_in[13];
    float* out = (float*)d_out;

    float* A1 = (float*)d_ws;                    // [N,64]
    float* B1 = A1 + (size_t)NN * 64;            // [N,64]
    float* A3 = B1 + (size_t)NN * 64;            // [N,128]
    float* B3 = A3 + (size_t)NN * 128;           // [N,128]
    unsigned short* WH = (unsigned short*)(B3 + (size_t)NN * 128);  // [116*512]
    unsigned short* WL = WH + NFRAG * 512;
    float* g  = A1;                              // [N,128] reuses A1/B1 (dead after k2)

    kw_kernel<<<(NFRAG * 64 + 255) / 256, 256, 0, stream>>>(W2, W3, W4, W5, W6, WH, WL);
    k1_kernel<<<NN * 64 / 256, 256, 0, stream>>>(x, W1, b1, A1, B1);
    k2_kernel<<<(NN + 63) / 64, 256, 0, stream>>>(col, A1, B1, WH, WL, b2, b3, A3, B3);
    k3_kernel<<<NN / 16, 256, 0, stream>>>(col, A3, B3,
                                           WH + (size_t)W4F * 512, WL + (size_t)W4F * 512,
                                           b4, g);
    k4_kernel<<<(NN + 63) / 64, 256, 0, stream>>>(g, WH, WL, b5, b6, out);
}